// Round 1
// baseline (5967.112 us; speedup 1.0000x reference)
//
#include <hip/hip_runtime.h>
#include <math.h>

#define N_NODES 100000
#define N_EDGES 3200000
#define NFEAT 128
#define NHID 128
#define NCLASS 8
#define BN_EPS 1e-5f

// ---------------- degree / norm ----------------

__global__ void k_init_deg(float* __restrict__ deg) {
    int i = blockIdx.x * blockDim.x + threadIdx.x;
    if (i < N_NODES) deg[i] = 1.0f;   // self-loop contributes 1
}

__global__ void k_edge_deg(const int* __restrict__ dst, float* __restrict__ deg) {
    int e = blockIdx.x * blockDim.x + threadIdx.x;
    if (e < N_EDGES) atomicAdd(&deg[dst[e]], 1.0f);
}

__global__ void k_dinv(float* __restrict__ deg) {
    int i = blockIdx.x * blockDim.x + threadIdx.x;
    if (i < N_NODES) deg[i] = rsqrtf(deg[i]);  // deg >= 1 always (self-loop)
}

// ---------------- h = x @ W  (fp32, LDS-tiled) ----------------
// block: 256 threads, 32 rows x 128 cols per block; K tiled by 32.

__global__ __launch_bounds__(256) void k_gemm(const float* __restrict__ x,
                                              const float* __restrict__ W,
                                              float* __restrict__ h) {
    __shared__ float sW[32][NHID];   // 16 KB
    __shared__ float sX[32][33];     // 4.2 KB (pad to kill bank conflicts)
    const int tid = threadIdx.x;
    const int c  = tid & 127;        // output col
    const int rg = tid >> 7;         // 0..1 row-group
    const int row0 = blockIdx.x * 32;

    float acc[16];
#pragma unroll
    for (int i = 0; i < 16; ++i) acc[i] = 0.f;

    for (int k0 = 0; k0 < NFEAT; k0 += 32) {
        // stage W tile 32x128 (4096 elems / 256 thr = 16 each), coalesced
#pragma unroll
        for (int i = 0; i < 16; ++i) {
            int idx = tid + i * 256;
            int kk = idx >> 7, cc = idx & 127;
            sW[kk][cc] = W[(k0 + kk) * NHID + cc];
        }
        // stage x tile 32x32 (1024 elems / 256 thr = 4 each)
#pragma unroll
        for (int i = 0; i < 4; ++i) {
            int idx = tid + i * 256;
            int rr = idx >> 5, kk = idx & 31;
            int r = row0 + rr;
            sX[rr][kk] = (r < N_NODES) ? x[(size_t)r * NFEAT + k0 + kk] : 0.f;
        }
        __syncthreads();
#pragma unroll
        for (int i = 0; i < 16; ++i) {
            int rr = rg + i * 2;
            float a = 0.f;
#pragma unroll
            for (int kk = 0; kk < 32; ++kk)
                a = fmaf(sX[rr][kk], sW[kk][c], a);
            acc[i] += a;
        }
        __syncthreads();
    }
#pragma unroll
    for (int i = 0; i < 16; ++i) {
        int r = row0 + rg + i * 2;
        if (r < N_NODES) h[(size_t)r * NHID + c] = acc[i];
    }
}

// ---------------- agg init with self-loop term ----------------
// agg[r][c] = dinv[r]^2 * h[r][c]

__global__ void k_selfinit(const float* __restrict__ dinv,
                           const float* __restrict__ h,
                           float* __restrict__ agg) {
    int t = blockIdx.x * blockDim.x + threadIdx.x;
    if (t >= N_NODES * NHID) return;
    int r = t >> 7;
    float di = dinv[r];
    agg[t] = di * di * h[t];
}

// ---------------- edge scatter: agg[dst] += dinv[src]*dinv[dst]*h[src] ----------------
// 32 lanes per edge, float4 gather + 4 fp32 atomics per lane.

__global__ __launch_bounds__(256) void k_scatter(const int* __restrict__ src,
                                                 const int* __restrict__ dst,
                                                 const float* __restrict__ dinv,
                                                 const float* __restrict__ h,
                                                 float* __restrict__ agg) {
    int t = blockIdx.x * blockDim.x + threadIdx.x;
    int e = t >> 5;
    int lane = t & 31;
    if (e >= N_EDGES) return;
    int s = src[e], d = dst[e];
    float n = dinv[s] * dinv[d];
    float4 v = *reinterpret_cast<const float4*>(h + (size_t)s * NHID + lane * 4);
    float* ap = agg + (size_t)d * NHID + lane * 4;
    atomicAdd(ap + 0, n * v.x);
    atomicAdd(ap + 1, n * v.y);
    atomicAdd(ap + 2, n * v.z);
    atomicAdd(ap + 3, n * v.w);
}

// ---------------- BN statistics ----------------

__global__ void k_zero_stats(float* __restrict__ stats) {
    int i = threadIdx.x;
    if (i < 256) stats[i] = 0.f;
}

__global__ __launch_bounds__(256) void k_stats(const float* __restrict__ agg,
                                               float* __restrict__ stats) {
    const int c = threadIdx.x & 127;
    const int half = threadIdx.x >> 7;
    float s = 0.f, s2 = 0.f;
    for (int r = blockIdx.x * 2 + half; r < N_NODES; r += gridDim.x * 2) {
        float v = agg[(size_t)r * NHID + c];
        s += v;
        s2 += v * v;
    }
    __shared__ float ls[256], ls2[256];
    ls[threadIdx.x] = s;
    ls2[threadIdx.x] = s2;
    __syncthreads();
    if (half == 0) {
        atomicAdd(&stats[c],       ls[c] + ls[c + 128]);
        atomicAdd(&stats[128 + c], ls2[c] + ls2[c + 128]);
    }
}

// scale[c] = gamma*invstd ; shift[c] = beta - mean*scale  (b_gc cancels in BN)
__global__ void k_bn_params(const float* __restrict__ stats,
                            const float* __restrict__ gamma,
                            const float* __restrict__ beta,
                            float* __restrict__ ss /* scale[128], shift[128] */) {
    int c = threadIdx.x;
    if (c >= NHID) return;
    float mean = stats[c] / (float)N_NODES;
    float var = stats[128 + c] / (float)N_NODES - mean * mean;
    var = fmaxf(var, 0.f);
    float inv = rsqrtf(var + BN_EPS);
    float sc = gamma[c] * inv;
    ss[c] = sc;
    ss[128 + c] = beta[c] - mean * sc;
}

// embed = agg*scale + shift  (in place over d_out embed region)
__global__ void k_bn_apply(float* __restrict__ embed,
                           const float* __restrict__ ss) {
    int t = blockIdx.x * blockDim.x + threadIdx.x;
    if (t >= N_NODES * NHID) return;
    int c = t & 127;
    embed[t] = fmaf(embed[t], ss[c], ss[128 + c]);
}

// out[r][j] = sum_k embed[r][k]*fc_w[j][k] + fc_b[j],  k<64
__global__ void k_fc(const float* __restrict__ embed,
                     const float* __restrict__ fc_w,
                     const float* __restrict__ fc_b,
                     float* __restrict__ out) {
    int t = blockIdx.x * blockDim.x + threadIdx.x;
    if (t >= N_NODES * NCLASS) return;
    int r = t >> 3, j = t & 7;
    const float* er = embed + (size_t)r * NHID;
    const float* wj = fc_w + j * (NHID / 2);
    float s = fc_b[j];
#pragma unroll
    for (int k = 0; k < NHID / 2; ++k) s = fmaf(er[k], wj[k], s);
    out[t] = s;
}

// ---------------- launch ----------------

extern "C" void kernel_launch(void* const* d_in, const int* in_sizes, int n_in,
                              void* d_out, int out_size, void* d_ws, size_t ws_size,
                              hipStream_t stream) {
    const float* x     = (const float*)d_in[0];
    const int*   ei    = (const int*)d_in[1];   // [2, E] int32
    const float* W     = (const float*)d_in[2];
    // d_in[3] = b_gc: cancels inside BatchNorm, unused.
    const float* gamma = (const float*)d_in[4];
    const float* beta  = (const float*)d_in[5];
    const float* fc_w  = (const float*)d_in[6];
    const float* fc_b  = (const float*)d_in[7];

    const int* src = ei;
    const int* dst = ei + N_EDGES;

    float* out   = (float*)d_out;                  // [N, 8]
    float* embed = (float*)d_out + (size_t)N_NODES * NCLASS;  // [N, 128] (= agg)

    // workspace layout
    char* ws = (char*)d_ws;
    float* h     = (float*)ws;                                   // 51.2 MB
    float* dinv  = (float*)(ws + (size_t)N_NODES * NHID * 4);    // 400 KB
    float* stats = dinv + N_NODES;                               // 256 f
    float* ss    = stats + 256;                                  // 256 f

    // degree + norm
    k_init_deg<<<(N_NODES + 255) / 256, 256, 0, stream>>>(dinv);
    k_edge_deg<<<(N_EDGES + 255) / 256, 256, 0, stream>>>(dst, dinv);
    k_dinv<<<(N_NODES + 255) / 256, 256, 0, stream>>>(dinv);

    // h = x @ W
    k_gemm<<<(N_NODES + 31) / 32, 256, 0, stream>>>(x, W, h);

    // agg = selfloop + scatter  (agg aliases embed region of d_out)
    k_selfinit<<<(N_NODES * NHID + 255) / 256, 256, 0, stream>>>(dinv, h, embed);
    {
        long long threads = (long long)N_EDGES * 32;
        int blocks = (int)((threads + 255) / 256);
        k_scatter<<<blocks, 256, 0, stream>>>(src, dst, dinv, h, embed);
    }

    // BatchNorm
    k_zero_stats<<<1, 256, 0, stream>>>(stats);
    k_stats<<<1024, 256, 0, stream>>>(embed, stats);
    k_bn_params<<<1, 128, 0, stream>>>(stats, gamma, beta, ss);
    k_bn_apply<<<(N_NODES * NHID + 255) / 256, 256, 0, stream>>>(embed, ss);

    // fc head
    k_fc<<<(N_NODES * NCLASS + 255) / 256, 256, 0, stream>>>(embed, fc_w, fc_b, out);
}

// Round 2
// 1311.228 us; speedup vs baseline: 4.5508x; 4.5508x over previous
//
#include <hip/hip_runtime.h>
#include <math.h>

#define N_NODES 100000
#define N_EDGES 3200000
#define NFEAT 128
#define NHID 128
#define NCLASS 8
#define BN_EPS 1e-5f

// ---------------- degree / norm ----------------

__global__ void k_zero_cnt(int* __restrict__ cnt) {
    int i = blockIdx.x * blockDim.x + threadIdx.x;
    if (i < N_NODES) cnt[i] = 0;
}

__global__ void k_count(const int* __restrict__ dst, int* __restrict__ cnt) {
    int e = blockIdx.x * blockDim.x + threadIdx.x;
    if (e < N_EDGES) atomicAdd(&cnt[dst[e]], 1);
}

// dinv[i] = rsqrt(cnt[i] + 1)   (self-loop adds 1)
__global__ void k_dinv(const int* __restrict__ cnt, float* __restrict__ dinv) {
    int i = blockIdx.x * blockDim.x + threadIdx.x;
    if (i < N_NODES) dinv[i] = rsqrtf((float)(cnt[i] + 1));
}

// ---------------- exclusive scan (single block, 1024 threads) ----------------
// off[0..N] = exclusive prefix of cnt; cursor = copy of off[0..N-1]

#define SCAN_T 1024
__global__ __launch_bounds__(SCAN_T) void k_scan(const int* __restrict__ cnt,
                                                 int* __restrict__ off,
                                                 int* __restrict__ cursor) {
    __shared__ int part[SCAN_T];
    const int t = threadIdx.x;
    const int chunk = (N_NODES + SCAN_T - 1) / SCAN_T;
    const int lo = t * chunk;
    const int hi = min(lo + chunk, N_NODES);
    int s = 0;
    for (int i = lo; i < hi; ++i) s += cnt[i];
    part[t] = s;
    __syncthreads();
    // Hillis-Steele inclusive scan over 1024 partials
    for (int d = 1; d < SCAN_T; d <<= 1) {
        int v = (t >= d) ? part[t - d] : 0;
        __syncthreads();
        part[t] += v;
        __syncthreads();
    }
    int run = part[t] - s;  // exclusive prefix for this chunk
    for (int i = lo; i < hi; ++i) {
        off[i] = run;
        cursor[i] = run;
        run += cnt[i];
    }
    if (t == SCAN_T - 1) off[N_NODES] = part[SCAN_T - 1];
}

// ---------------- bucket edges by dst ----------------

__global__ void k_bucket(const int* __restrict__ src, const int* __restrict__ dst,
                         int* __restrict__ cursor, int* __restrict__ esrc) {
    int e = blockIdx.x * blockDim.x + threadIdx.x;
    if (e >= N_EDGES) return;
    int d = dst[e];
    int pos = atomicAdd(&cursor[d], 1);
    esrc[pos] = src[e];
}

// ---------------- h = x @ W  (fp32, LDS-tiled) ----------------

__global__ __launch_bounds__(256) void k_gemm(const float* __restrict__ x,
                                              const float* __restrict__ W,
                                              float* __restrict__ h) {
    __shared__ float sW[32][NHID];
    __shared__ float sX[32][33];
    const int tid = threadIdx.x;
    const int c  = tid & 127;
    const int rg = tid >> 7;
    const int row0 = blockIdx.x * 32;

    float acc[16];
#pragma unroll
    for (int i = 0; i < 16; ++i) acc[i] = 0.f;

    for (int k0 = 0; k0 < NFEAT; k0 += 32) {
#pragma unroll
        for (int i = 0; i < 16; ++i) {
            int idx = tid + i * 256;
            int kk = idx >> 7, cc = idx & 127;
            sW[kk][cc] = W[(k0 + kk) * NHID + cc];
        }
#pragma unroll
        for (int i = 0; i < 4; ++i) {
            int idx = tid + i * 256;
            int rr = idx >> 5, kk = idx & 31;
            int r = row0 + rr;
            sX[rr][kk] = (r < N_NODES) ? x[(size_t)r * NFEAT + k0 + kk] : 0.f;
        }
        __syncthreads();
#pragma unroll
        for (int i = 0; i < 16; ++i) {
            int rr = rg + i * 2;
            float a = 0.f;
#pragma unroll
            for (int kk = 0; kk < 32; ++kk)
                a = fmaf(sX[rr][kk], sW[kk][c], a);
            acc[i] += a;
        }
        __syncthreads();
    }
#pragma unroll
    for (int i = 0; i < 16; ++i) {
        int r = row0 + rg + i * 2;
        if (r < N_NODES) h[(size_t)r * NHID + c] = acc[i];
    }
}

// ---------------- aggregation: one wave per node, no atomics ----------------
// acc(float2/lane) = dinv[n]^2 * h[n] + sum_e dinv[src]*dinv[n] * h[src]

__global__ __launch_bounds__(256) void k_agg(const int* __restrict__ off,
                                             const int* __restrict__ esrc,
                                             const float* __restrict__ dinv,
                                             const float* __restrict__ h,
                                             float* __restrict__ agg) {
    const int wave = (blockIdx.x << 2) | (threadIdx.x >> 6);  // node id
    const int lane = threadIdx.x & 63;
    if (wave >= N_NODES) return;
    const float2* __restrict__ h2 = (const float2*)h;

    const float dn = dinv[wave];
    float2 acc = h2[(size_t)wave * 64 + lane];
    acc.x *= dn * dn;
    acc.y *= dn * dn;

    const int begin = off[wave];
    const int end   = off[wave + 1];
    for (int base = begin; base < end; base += 64) {
        const int m = end - base;  // >=1; use min(m,64) iterations
        int   sv = 0;
        float dv = 0.f;
        if (lane < m) {
            sv = esrc[base + lane];
            dv = dinv[sv];
        }
        const int iters = m < 64 ? m : 64;
        for (int k = 0; k < iters; ++k) {
            int   s = __shfl(sv, k);
            float w = __shfl(dv, k) * dn;
            float2 v = h2[(size_t)s * 64 + lane];
            acc.x = fmaf(w, v.x, acc.x);
            acc.y = fmaf(w, v.y, acc.y);
        }
    }
    float2* __restrict__ agg2 = (float2*)agg;
    agg2[(size_t)wave * 64 + lane] = acc;
}

// ---------------- fallback (round-1 atomic scatter) ----------------

__global__ void k_selfinit(const float* __restrict__ dinv,
                           const float* __restrict__ h,
                           float* __restrict__ agg) {
    int t = blockIdx.x * blockDim.x + threadIdx.x;
    if (t >= N_NODES * NHID) return;
    int r = t >> 7;
    float di = dinv[r];
    agg[t] = di * di * h[t];
}

__global__ __launch_bounds__(256) void k_scatter(const int* __restrict__ src,
                                                 const int* __restrict__ dst,
                                                 const float* __restrict__ dinv,
                                                 const float* __restrict__ h,
                                                 float* __restrict__ agg) {
    int t = blockIdx.x * blockDim.x + threadIdx.x;
    int e = t >> 5;
    int lane = t & 31;
    if (e >= N_EDGES) return;
    int s = src[e], d = dst[e];
    float n = dinv[s] * dinv[d];
    float4 v = *reinterpret_cast<const float4*>(h + (size_t)s * NHID + lane * 4);
    float* ap = agg + (size_t)d * NHID + lane * 4;
    atomicAdd(ap + 0, n * v.x);
    atomicAdd(ap + 1, n * v.y);
    atomicAdd(ap + 2, n * v.z);
    atomicAdd(ap + 3, n * v.w);
}

// ---------------- BatchNorm ----------------

__global__ void k_zero_stats(float* __restrict__ stats) {
    int i = threadIdx.x;
    if (i < 256) stats[i] = 0.f;
}

__global__ __launch_bounds__(256) void k_stats(const float* __restrict__ agg,
                                               float* __restrict__ stats) {
    const int c = threadIdx.x & 127;
    const int half = threadIdx.x >> 7;
    float s = 0.f, s2 = 0.f;
    for (int r = blockIdx.x * 2 + half; r < N_NODES; r += gridDim.x * 2) {
        float v = agg[(size_t)r * NHID + c];
        s += v;
        s2 += v * v;
    }
    __shared__ float ls[256], ls2[256];
    ls[threadIdx.x] = s;
    ls2[threadIdx.x] = s2;
    __syncthreads();
    if (half == 0) {
        atomicAdd(&stats[c],       ls[c] + ls[c + 128]);
        atomicAdd(&stats[128 + c], ls2[c] + ls2[c + 128]);
    }
}

__global__ void k_bn_params(const float* __restrict__ stats,
                            const float* __restrict__ gamma,
                            const float* __restrict__ beta,
                            float* __restrict__ ss) {
    int c = threadIdx.x;
    if (c >= NHID) return;
    float mean = stats[c] / (float)N_NODES;
    float var = stats[128 + c] / (float)N_NODES - mean * mean;
    var = fmaxf(var, 0.f);
    float inv = rsqrtf(var + BN_EPS);
    float sc = gamma[c] * inv;
    ss[c] = sc;
    ss[128 + c] = beta[c] - mean * sc;
}

__global__ void k_bn_apply(float* __restrict__ embed,
                           const float* __restrict__ ss) {
    int t = blockIdx.x * blockDim.x + threadIdx.x;
    if (t >= N_NODES * NHID) return;
    int c = t & 127;
    embed[t] = fmaf(embed[t], ss[c], ss[128 + c]);
}

__global__ void k_fc(const float* __restrict__ embed,
                     const float* __restrict__ fc_w,
                     const float* __restrict__ fc_b,
                     float* __restrict__ out) {
    int t = blockIdx.x * blockDim.x + threadIdx.x;
    if (t >= N_NODES * NCLASS) return;
    int r = t >> 3, j = t & 7;
    const float* er = embed + (size_t)r * NHID;
    const float* wj = fc_w + j * (NHID / 2);
    float s = fc_b[j];
#pragma unroll
    for (int k = 0; k < NHID / 2; ++k) s = fmaf(er[k], wj[k], s);
    out[t] = s;
}

// ---------------- launch ----------------

extern "C" void kernel_launch(void* const* d_in, const int* in_sizes, int n_in,
                              void* d_out, int out_size, void* d_ws, size_t ws_size,
                              hipStream_t stream) {
    const float* x     = (const float*)d_in[0];
    const int*   ei    = (const int*)d_in[1];
    const float* W     = (const float*)d_in[2];
    // d_in[3] = b_gc: cancels inside BatchNorm, unused.
    const float* gamma = (const float*)d_in[4];
    const float* beta  = (const float*)d_in[5];
    const float* fc_w  = (const float*)d_in[6];
    const float* fc_b  = (const float*)d_in[7];

    const int* src = ei;
    const int* dst = ei + N_EDGES;

    float* out   = (float*)d_out;
    float* embed = (float*)d_out + (size_t)N_NODES * NCLASS;  // agg lives here

    // workspace layout
    char* ws = (char*)d_ws;
    size_t o = 0;
    float* h = (float*)(ws + o);      o += (size_t)N_NODES * NHID * 4;   // 51.2 MB
    float* dinv = (float*)(ws + o);   o += (size_t)N_NODES * 4;
    float* stats = (float*)(ws + o);  o += 256 * 4;
    float* ss = (float*)(ws + o);     o += 256 * 4;
    size_t o_small = o;
    int* cnt    = (int*)(ws + o);     o += (size_t)N_NODES * 4;
    int* off    = (int*)(ws + o);     o += (size_t)(N_NODES + 1) * 4;
    int* cursor = (int*)(ws + o);     o += (size_t)N_NODES * 4;
    int* esrc   = (int*)(ws + o);     o += (size_t)N_EDGES * 4;          // 12.8 MB
    const bool csr_ok = (o <= ws_size);

    // h = x @ W (independent of graph prep; issue early)
    k_gemm<<<(N_NODES + 31) / 32, 256, 0, stream>>>(x, W, h);

    if (csr_ok) {
        k_zero_cnt<<<(N_NODES + 255) / 256, 256, 0, stream>>>(cnt);
        k_count<<<(N_EDGES + 255) / 256, 256, 0, stream>>>(dst, cnt);
        k_dinv<<<(N_NODES + 255) / 256, 256, 0, stream>>>(cnt, dinv);
        k_scan<<<1, SCAN_T, 0, stream>>>(cnt, off, cursor);
        k_bucket<<<(N_EDGES + 255) / 256, 256, 0, stream>>>(src, dst, cursor, esrc);
        k_agg<<<(N_NODES + 3) / 4, 256, 0, stream>>>(off, esrc, dinv, h, embed);
    } else {
        // fallback: atomic scatter (uses only h+dinv region)
        (void)o_small;
        k_zero_cnt<<<(N_NODES + 255) / 256, 256, 0, stream>>>((int*)dinv);
        k_count<<<(N_EDGES + 255) / 256, 256, 0, stream>>>(dst, (int*)dinv);
        k_dinv<<<(N_NODES + 255) / 256, 256, 0, stream>>>((int*)dinv, dinv);
        k_selfinit<<<(N_NODES * NHID + 255) / 256, 256, 0, stream>>>(dinv, h, embed);
        long long threads = (long long)N_EDGES * 32;
        int blocks = (int)((threads + 255) / 256);
        k_scatter<<<blocks, 256, 0, stream>>>(src, dst, dinv, h, embed);
    }

    // BatchNorm
    k_zero_stats<<<1, 256, 0, stream>>>(stats);
    k_stats<<<1024, 256, 0, stream>>>(embed, stats);
    k_bn_params<<<1, 128, 0, stream>>>(stats, gamma, beta, ss);
    k_bn_apply<<<(N_NODES * NHID + 255) / 256, 256, 0, stream>>>(embed, ss);

    // fc head
    k_fc<<<(N_NODES * NCLASS + 255) / 256, 256, 0, stream>>>(embed, fc_w, fc_b, out);
}

// Round 3
// 910.299 us; speedup vs baseline: 6.5551x; 1.4404x over previous
//
#include <hip/hip_runtime.h>
#include <math.h>

#define N_NODES 100000
#define N_EDGES 3200000
#define NFEAT 128
#define NHID 128
#define NCLASS 8
#define BN_EPS 1e-5f

typedef __attribute__((ext_vector_type(8))) short short8;
typedef __attribute__((ext_vector_type(4))) float f32x4;

__device__ __forceinline__ short f2bf(float f) {
    unsigned u = __float_as_uint(f);
    u += 0x7fffu + ((u >> 16) & 1u);   // round-to-nearest-even
    return (short)(u >> 16);
}
__device__ __forceinline__ float bf_lo(unsigned u) { return __uint_as_float(u << 16); }
__device__ __forceinline__ float bf_hi(unsigned u) { return __uint_as_float(u & 0xffff0000u); }

// ---------------- graph prep ----------------

__global__ void k_zero_cnt(int* __restrict__ cnt) {
    int i = blockIdx.x * blockDim.x + threadIdx.x;
    if (i < N_NODES) cnt[i] = 0;
}

__global__ void k_count(const int* __restrict__ dst, int* __restrict__ cnt) {
    int e = blockIdx.x * blockDim.x + threadIdx.x;
    if (e < N_EDGES) atomicAdd(&cnt[dst[e]], 1);
}

__global__ void k_dinv(const int* __restrict__ cnt, float* __restrict__ dinv) {
    int i = blockIdx.x * blockDim.x + threadIdx.x;
    if (i < N_NODES) dinv[i] = rsqrtf((float)(cnt[i] + 1));
}

#define SCAN_T 1024
__global__ __launch_bounds__(SCAN_T) void k_scan(const int* __restrict__ cnt,
                                                 int* __restrict__ off,
                                                 int* __restrict__ cursor) {
    __shared__ int part[SCAN_T];
    const int t = threadIdx.x;
    const int chunk = (N_NODES + SCAN_T - 1) / SCAN_T;
    const int lo = t * chunk;
    const int hi = min(lo + chunk, N_NODES);
    int s = 0;
    for (int i = lo; i < hi; ++i) s += cnt[i];
    part[t] = s;
    __syncthreads();
    for (int d = 1; d < SCAN_T; d <<= 1) {
        int v = (t >= d) ? part[t - d] : 0;
        __syncthreads();
        part[t] += v;
        __syncthreads();
    }
    int run = part[t] - s;
    for (int i = lo; i < hi; ++i) {
        off[i] = run;
        cursor[i] = run;
        run += cnt[i];
    }
    if (t == SCAN_T - 1) off[N_NODES] = part[SCAN_T - 1];
}

__global__ void k_bucket(const int* __restrict__ src, const int* __restrict__ dst,
                         int* __restrict__ cursor, int* __restrict__ esrc) {
    int e = blockIdx.x * blockDim.x + threadIdx.x;
    if (e >= N_EDGES) return;
    int d = dst[e];
    int pos = atomicAdd(&cursor[d], 1);
    esrc[pos] = src[e];
}

// ---------------- W transpose+convert: Wt[n][k] = bf16(W[k][n]) ----------------

__global__ void k_wt(const float* __restrict__ W, unsigned short* __restrict__ Wt) {
    int idx = blockIdx.x * blockDim.x + threadIdx.x;
    if (idx >= NFEAT * NHID) return;
    int k = idx >> 7, n = idx & 127;
    Wt[n * NFEAT + k] = (unsigned short)f2bf(W[idx]);
}

// ---------------- MFMA GEMM: hb[r] = bf16(dinv[r] * (x @ W)[r]) ----------------
// block = 256 thr (4 waves), 64 rows/block; W fully in LDS (padded stride 136).

#define WSTRIDE 136
__global__ __launch_bounds__(256) void k_gemm(const float* __restrict__ x,
                                              const unsigned short* __restrict__ Wt,
                                              const float* __restrict__ dinv,
                                              unsigned short* __restrict__ hb) {
    __shared__ short wlds[NHID * WSTRIDE];   // 34.8 KB
    const int tid = threadIdx.x;

    // stage Wt -> LDS (uint view; row n lives at short-offset n*136 = uint-offset n*68)
    const unsigned* Wt32 = (const unsigned*)Wt;
    unsigned* wl32 = (unsigned*)wlds;
#pragma unroll
    for (int i = 0; i < 32; ++i) {
        int d = tid + i * 256;          // 0..8191 dwords
        int n = d >> 6, kp = d & 63;
        wl32[n * (WSTRIDE / 2) + kp] = Wt32[d];
    }
    __syncthreads();

    const int wid = tid >> 6, lane = tid & 63;
    const int qw = lane >> 4, lr = lane & 15;
    const int arow = blockIdx.x * 64 + wid * 16 + lr;   // A-operand row for this lane
    const bool avalid = arow < N_NODES;

    // A fragments: lane holds x[arow][ks*32 + qw*8 .. +8), fp32 -> bf16
    short8 a[4];
#pragma unroll
    for (int ks = 0; ks < 4; ++ks) {
        if (avalid) {
            const float* p = x + (size_t)arow * NFEAT + ks * 32 + qw * 8;
            float4 v0 = *(const float4*)p;
            float4 v1 = *(const float4*)(p + 4);
            short8 t;
            t[0] = f2bf(v0.x); t[1] = f2bf(v0.y); t[2] = f2bf(v0.z); t[3] = f2bf(v0.w);
            t[4] = f2bf(v1.x); t[5] = f2bf(v1.y); t[6] = f2bf(v1.z); t[7] = f2bf(v1.w);
            a[ks] = t;
        } else {
            short8 t; 
#pragma unroll
            for (int j = 0; j < 8; ++j) t[j] = 0;
            a[ks] = t;
        }
    }

    f32x4 acc[8];
#pragma unroll
    for (int nt = 0; nt < 8; ++nt) acc[nt] = (f32x4){0.f, 0.f, 0.f, 0.f};

#pragma unroll
    for (int nt = 0; nt < 8; ++nt) {
#pragma unroll
        for (int ks = 0; ks < 4; ++ks) {
            short8 b = *(const short8*)&wlds[(nt * 16 + lr) * WSTRIDE + ks * 32 + qw * 8];
            acc[nt] = __builtin_amdgcn_mfma_f32_16x16x32_bf16(a[ks], b, acc[nt], 0, 0, 0);
        }
    }

    // Epilogue: D lane layout col = lr, row = qw*4 + j. Scale by dinv, store bf16.
    const int rbase = blockIdx.x * 64 + wid * 16 + qw * 4;
    float dv[4];
#pragma unroll
    for (int j = 0; j < 4; ++j) dv[j] = (rbase + j < N_NODES) ? dinv[rbase + j] : 0.f;
#pragma unroll
    for (int j = 0; j < 4; ++j) {
        int r = rbase + j;
        if (r >= N_NODES) continue;
#pragma unroll
        for (int nt = 0; nt < 8; ++nt)
            hb[(size_t)r * NHID + nt * 16 + lr] = (unsigned short)f2bf(dv[j] * acc[nt][j]);
    }
}

// ---------------- aggregation: one wave per node ----------------
// agg[n] = dinv[n] * ( hb[n] + sum_{e in CSR[n]} hb[src_e] )   (dinv[src] folded into hb)

__global__ __launch_bounds__(256) void k_agg(const int* __restrict__ off,
                                             const int* __restrict__ esrc,
                                             const float* __restrict__ dinv,
                                             const unsigned* __restrict__ hb32,
                                             float* __restrict__ agg) {
    const int node = (blockIdx.x << 2) | (threadIdx.x >> 6);
    const int lane = threadIdx.x & 63;
    if (node >= N_NODES) return;

    unsigned v = hb32[(size_t)node * 64 + lane];
    float ax = bf_lo(v), ay = bf_hi(v);

    const int begin = off[node];
    const int end   = off[node + 1];
    for (int base = begin; base < end; base += 64) {
        const int m = end - base;
        int sv = (lane < m) ? esrc[base + lane] : 0;
        const int iters = m < 64 ? m : 64;
        for (int k = 0; k < iters; ++k) {
            int s = __shfl(sv, k);
            unsigned u = hb32[(size_t)s * 64 + lane];
            ax += bf_lo(u);
            ay += bf_hi(u);
        }
    }
    const float dn = dinv[node];
    float2 o; o.x = ax * dn; o.y = ay * dn;
    ((float2*)agg)[(size_t)node * 64 + lane] = o;
}

// ---------------- BatchNorm ----------------

__global__ void k_zero_stats(float* __restrict__ stats) {
    int i = threadIdx.x;
    if (i < 256) stats[i] = 0.f;
}

__global__ __launch_bounds__(256) void k_stats(const float* __restrict__ agg,
                                               float* __restrict__ stats) {
    const int c = threadIdx.x & 127;
    const int half = threadIdx.x >> 7;
    float s = 0.f, s2 = 0.f;
    for (int r = blockIdx.x * 2 + half; r < N_NODES; r += gridDim.x * 2) {
        float v = agg[(size_t)r * NHID + c];
        s += v;
        s2 += v * v;
    }
    __shared__ float ls[256], ls2[256];
    ls[threadIdx.x] = s;
    ls2[threadIdx.x] = s2;
    __syncthreads();
    if (half == 0) {
        atomicAdd(&stats[c],       ls[c] + ls[c + 128]);
        atomicAdd(&stats[128 + c], ls2[c] + ls2[c + 128]);
    }
}

__global__ void k_bn_params(const float* __restrict__ stats,
                            const float* __restrict__ gamma,
                            const float* __restrict__ beta,
                            float* __restrict__ ss) {
    int c = threadIdx.x;
    if (c >= NHID) return;
    float mean = stats[c] / (float)N_NODES;
    float var = stats[128 + c] / (float)N_NODES - mean * mean;
    var = fmaxf(var, 0.f);
    float inv = rsqrtf(var + BN_EPS);
    float sc = gamma[c] * inv;
    ss[c] = sc;
    ss[128 + c] = beta[c] - mean * sc;
}

__global__ void k_bn_apply(float* __restrict__ embed,
                           const float* __restrict__ ss) {
    int t = blockIdx.x * blockDim.x + threadIdx.x;
    if (t >= N_NODES * NHID) return;
    int c = t & 127;
    embed[t] = fmaf(embed[t], ss[c], ss[128 + c]);
}

// ---------------- fc head (LDS-staged) ----------------

__global__ __launch_bounds__(256) void k_fc(const float* __restrict__ embed,
                                            const float* __restrict__ fc_w,
                                            const float* __restrict__ fc_b,
                                            float* __restrict__ out) {
    __shared__ float se[32][65];
    __shared__ float sw[8][65];
    __shared__ float sb[8];
    const int tid = threadIdx.x;
    const int row0 = blockIdx.x * 32;
#pragma unroll
    for (int i = 0; i < 2; ++i) {
        int d = tid + i * 256;   // 0..511
        sw[d >> 6][d & 63] = fc_w[d];
    }
    if (tid < 8) sb[tid] = fc_b[tid];
#pragma unroll
    for (int i = 0; i < 8; ++i) {
        int d = tid + i * 256;   // 0..2047
        int r = d >> 6, c = d & 63;
        se[r][c] = (row0 + r < N_NODES) ? embed[(size_t)(row0 + r) * NHID + c] : 0.f;
    }
    __syncthreads();
    const int r = tid >> 3, j = tid & 7;
    float s = sb[j];
#pragma unroll
    for (int k = 0; k < NHID / 2; ++k) s = fmaf(se[r][k], sw[j][k], s);
    if (row0 + r < N_NODES) out[(size_t)(row0 + r) * NCLASS + j] = s;
}

// ---------------- launch ----------------

extern "C" void kernel_launch(void* const* d_in, const int* in_sizes, int n_in,
                              void* d_out, int out_size, void* d_ws, size_t ws_size,
                              hipStream_t stream) {
    const float* x     = (const float*)d_in[0];
    const int*   ei    = (const int*)d_in[1];
    const float* W     = (const float*)d_in[2];
    // d_in[3] = b_gc: cancels inside BatchNorm, unused.
    const float* gamma = (const float*)d_in[4];
    const float* beta  = (const float*)d_in[5];
    const float* fc_w  = (const float*)d_in[6];
    const float* fc_b  = (const float*)d_in[7];

    const int* src = ei;
    const int* dst = ei + N_EDGES;

    float* out   = (float*)d_out;
    float* embed = (float*)d_out + (size_t)N_NODES * NCLASS;  // agg lives here

    // workspace layout (~40 MB)
    char* ws = (char*)d_ws;
    size_t o = 0;
    unsigned short* Wt = (unsigned short*)(ws + o); o += (size_t)NFEAT * NHID * 2;   // 32 KB
    unsigned short* hb = (unsigned short*)(ws + o); o += (size_t)N_NODES * NHID * 2; // 25.6 MB
    float* dinv  = (float*)(ws + o); o += (size_t)N_NODES * 4;
    float* stats = (float*)(ws + o); o += 256 * 4;
    float* ss    = (float*)(ws + o); o += 256 * 4;
    int* cnt     = (int*)(ws + o);   o += (size_t)N_NODES * 4;
    int* off     = (int*)(ws + o);   o += (size_t)(N_NODES + 1) * 4;
    int* cursor  = (int*)(ws + o);   o += (size_t)N_NODES * 4;
    int* esrc    = (int*)(ws + o);   o += (size_t)N_EDGES * 4;                        // 12.8 MB

    // graph prep
    k_zero_cnt<<<(N_NODES + 255) / 256, 256, 0, stream>>>(cnt);
    k_count<<<(N_EDGES + 255) / 256, 256, 0, stream>>>(dst, cnt);
    k_dinv<<<(N_NODES + 255) / 256, 256, 0, stream>>>(cnt, dinv);
    k_scan<<<1, SCAN_T, 0, stream>>>(cnt, off, cursor);
    k_bucket<<<(N_EDGES + 255) / 256, 256, 0, stream>>>(src, dst, cursor, esrc);

    // hb = bf16(dinv * (x @ W))
    k_wt<<<(NFEAT * NHID + 255) / 256, 256, 0, stream>>>(W, Wt);
    k_gemm<<<(N_NODES + 63) / 64, 256, 0, stream>>>(x, Wt, dinv, hb);

    // aggregation (no atomics)
    k_agg<<<(N_NODES + 3) / 4, 256, 0, stream>>>(off, esrc, dinv, (const unsigned*)hb, embed);

    // BatchNorm
    k_zero_stats<<<1, 256, 0, stream>>>(stats);
    k_stats<<<1024, 256, 0, stream>>>(embed, stats);
    k_bn_params<<<1, 128, 0, stream>>>(stats, gamma, beta, ss);
    k_bn_apply<<<(N_NODES * NHID + 255) / 256, 256, 0, stream>>>(embed, ss);

    // fc head
    k_fc<<<(N_NODES + 31) / 32, 256, 0, stream>>>(embed, fc_w, fc_b, out);
}

// Round 4
// 403.690 us; speedup vs baseline: 14.7814x; 2.2549x over previous
//
#include <hip/hip_runtime.h>
#include <math.h>

#define N_NODES 100000
#define N_EDGES 3200000
#define NFEAT 128
#define NHID 128
#define NCLASS 8
#define BN_EPS 1e-5f
#define NBC 391            // coarse buckets of 256 nodes: ceil(100000/256)
#define PART_BLOCKS 782    // ceil(N_EDGES / 4096)

typedef __attribute__((ext_vector_type(8))) short short8;
typedef __attribute__((ext_vector_type(4))) float f32x4;

__device__ __forceinline__ short f2bf(float f) {
    unsigned u = __float_as_uint(f);
    u += 0x7fffu + ((u >> 16) & 1u);   // round-to-nearest-even
    return (short)(u >> 16);
}
__device__ __forceinline__ float bf_lo(unsigned u) { return __uint_as_float(u << 16); }
__device__ __forceinline__ float bf_hi(unsigned u) { return __uint_as_float(u & 0xffff0000u); }

// ---------------- two-level counting sort ----------------

__global__ void k_zero_small(int* __restrict__ p, int n) {
    int i = blockIdx.x * blockDim.x + threadIdx.x;
    if (i < n) p[i] = 0;
}

// coarse histogram over dst>>8
__global__ __launch_bounds__(256) void k_chist(const int* __restrict__ dst,
                                               int* __restrict__ ghist) {
    __shared__ int lh[NBC];
    const int tid = threadIdx.x;
    for (int i = tid; i < NBC; i += 256) lh[i] = 0;
    __syncthreads();
    const int e0 = blockIdx.x * 4096 + tid;
#pragma unroll
    for (int i = 0; i < 16; ++i) {
        int e = e0 + i * 256;
        if (e < N_EDGES) atomicAdd(&lh[dst[e] >> 8], 1);
    }
    __syncthreads();
    for (int i = tid; i < NBC; i += 256) {
        int c = lh[i];
        if (c) atomicAdd(&ghist[i], c);
    }
}

// scan coarse hist -> coff[0..NBC], init ccur, write off[N_NODES]
__global__ __launch_bounds__(512) void k_cscan(const int* __restrict__ ghist,
                                               int* __restrict__ coff,
                                               int* __restrict__ ccur,
                                               int* __restrict__ off) {
    __shared__ int tmp[512];
    const int t = threadIdx.x;
    int v = (t < NBC) ? ghist[t] : 0;
    tmp[t] = v;
    __syncthreads();
    for (int d = 1; d < 512; d <<= 1) {
        int u = (t >= d) ? tmp[t - d] : 0;
        __syncthreads();
        tmp[t] += u;
        __syncthreads();
    }
    int excl = tmp[t] - v;
    if (t < NBC) {
        coff[t] = excl;
        ccur[t] = excl;
    }
    if (t == NBC - 1) {
        coff[NBC] = tmp[t];
        off[N_NODES] = tmp[t];
    }
}

// scatter (src,dst) pairs into coarse regions
__global__ __launch_bounds__(256) void k_part(const int* __restrict__ src,
                                              const int* __restrict__ dst,
                                              int* __restrict__ ccur,
                                              int2* __restrict__ epair) {
    __shared__ int lh[NBC];
    __shared__ int lbase[NBC];
    const int tid = threadIdx.x;
    for (int i = tid; i < NBC; i += 256) lh[i] = 0;
    __syncthreads();
    const int e0 = blockIdx.x * 4096 + tid;
    int sv[16], dv[16], rk[16];
#pragma unroll
    for (int i = 0; i < 16; ++i) {
        int e = e0 + i * 256;
        if (e < N_EDGES) {
            sv[i] = src[e];
            dv[i] = dst[e];
            rk[i] = atomicAdd(&lh[dv[i] >> 8], 1);
        } else dv[i] = -1;
    }
    __syncthreads();
    for (int i = tid; i < NBC; i += 256) {
        int c = lh[i];
        lbase[i] = c ? atomicAdd(&ccur[i], c) : 0;
    }
    __syncthreads();
#pragma unroll
    for (int i = 0; i < 16; ++i) {
        if (dv[i] >= 0) {
            int b = dv[i] >> 8;
            epair[lbase[b] + rk[i]] = make_int2(sv[i], dv[i]);
        }
    }
}

// per-coarse-bucket fine sort: exact CSR off/dinv/esrc
__global__ __launch_bounds__(256) void k_fine(const int2* __restrict__ epair,
                                              const int* __restrict__ coff,
                                              int* __restrict__ off,
                                              float* __restrict__ dinv,
                                              int* __restrict__ esrc) {
    __shared__ int lh[256], lcur[256], lsc[256];
    const int tid = threadIdx.x;
    const int b = blockIdx.x;
    const int node0 = b << 8;
    const int span = min(256, N_NODES - node0);
    lh[tid] = 0;
    __syncthreads();
    const int lo = coff[b], hiEnd = coff[b + 1];
    for (int i = lo + tid; i < hiEnd; i += 256)
        atomicAdd(&lh[epair[i].y & 255], 1);
    __syncthreads();
    int v = lh[tid];
    lsc[tid] = v;
    __syncthreads();
    for (int d = 1; d < 256; d <<= 1) {
        int u = (tid >= d) ? lsc[tid - d] : 0;
        __syncthreads();
        lsc[tid] += u;
        __syncthreads();
    }
    int excl = lsc[tid] - v;
    lcur[tid] = excl;
    if (tid < span) {
        off[node0 + tid] = lo + excl;
        dinv[node0 + tid] = rsqrtf((float)(v + 1));
    }
    __syncthreads();
    for (int i = lo + tid; i < hiEnd; i += 256) {
        int2 p = epair[i];
        int pos = atomicAdd(&lcur[p.y & 255], 1);
        esrc[lo + pos] = p.x;
    }
}

// ---------------- W transpose+convert: Wt[n][k] = bf16(W[k][n]) ----------------

__global__ void k_wt(const float* __restrict__ W, unsigned short* __restrict__ Wt) {
    int idx = blockIdx.x * blockDim.x + threadIdx.x;
    if (idx >= NFEAT * NHID) return;
    int k = idx >> 7, n = idx & 127;
    Wt[n * NFEAT + k] = (unsigned short)f2bf(W[idx]);
}

// ---------------- MFMA GEMM: hb[r] = bf16(dinv[r] * (x @ W)[r]) ----------------

#define WSTRIDE 136
__global__ __launch_bounds__(256) void k_gemm(const float* __restrict__ x,
                                              const unsigned short* __restrict__ Wt,
                                              const float* __restrict__ dinv,
                                              unsigned short* __restrict__ hb) {
    __shared__ short wlds[NHID * WSTRIDE];
    const int tid = threadIdx.x;

    const unsigned* Wt32 = (const unsigned*)Wt;
    unsigned* wl32 = (unsigned*)wlds;
#pragma unroll
    for (int i = 0; i < 32; ++i) {
        int d = tid + i * 256;
        int n = d >> 6, kp = d & 63;
        wl32[n * (WSTRIDE / 2) + kp] = Wt32[d];
    }
    __syncthreads();

    const int wid = tid >> 6, lane = tid & 63;
    const int qw = lane >> 4, lr = lane & 15;
    const int arow = blockIdx.x * 64 + wid * 16 + lr;
    const bool avalid = arow < N_NODES;

    short8 a[4];
#pragma unroll
    for (int ks = 0; ks < 4; ++ks) {
        if (avalid) {
            const float* p = x + (size_t)arow * NFEAT + ks * 32 + qw * 8;
            float4 v0 = *(const float4*)p;
            float4 v1 = *(const float4*)(p + 4);
            short8 t;
            t[0] = f2bf(v0.x); t[1] = f2bf(v0.y); t[2] = f2bf(v0.z); t[3] = f2bf(v0.w);
            t[4] = f2bf(v1.x); t[5] = f2bf(v1.y); t[6] = f2bf(v1.z); t[7] = f2bf(v1.w);
            a[ks] = t;
        } else {
            short8 t;
#pragma unroll
            for (int j = 0; j < 8; ++j) t[j] = 0;
            a[ks] = t;
        }
    }

    f32x4 acc[8];
#pragma unroll
    for (int nt = 0; nt < 8; ++nt) acc[nt] = (f32x4){0.f, 0.f, 0.f, 0.f};

#pragma unroll
    for (int nt = 0; nt < 8; ++nt) {
#pragma unroll
        for (int ks = 0; ks < 4; ++ks) {
            short8 bfr = *(const short8*)&wlds[(nt * 16 + lr) * WSTRIDE + ks * 32 + qw * 8];
            acc[nt] = __builtin_amdgcn_mfma_f32_16x16x32_bf16(a[ks], bfr, acc[nt], 0, 0, 0);
        }
    }

    const int rbase = blockIdx.x * 64 + wid * 16 + qw * 4;
    float dv[4];
#pragma unroll
    for (int j = 0; j < 4; ++j) dv[j] = (rbase + j < N_NODES) ? dinv[rbase + j] : 0.f;
#pragma unroll
    for (int j = 0; j < 4; ++j) {
        int r = rbase + j;
        if (r >= N_NODES) continue;
#pragma unroll
        for (int nt = 0; nt < 8; ++nt)
            hb[(size_t)r * NHID + nt * 16 + lr] = (unsigned short)f2bf(dv[j] * acc[nt][j]);
    }
}

// ---------------- aggregation: one wave per node ----------------

__global__ __launch_bounds__(256) void k_agg(const int* __restrict__ off,
                                             const int* __restrict__ esrc,
                                             const float* __restrict__ dinv,
                                             const unsigned* __restrict__ hb32,
                                             float* __restrict__ agg) {
    const int node = (blockIdx.x << 2) | (threadIdx.x >> 6);
    const int lane = threadIdx.x & 63;
    if (node >= N_NODES) return;

    unsigned v = hb32[(size_t)node * 64 + lane];
    float ax = bf_lo(v), ay = bf_hi(v);

    const int begin = off[node];
    const int end   = off[node + 1];
    for (int base = begin; base < end; base += 64) {
        const int m = end - base;
        int sv = (lane < m) ? esrc[base + lane] : 0;
        const int iters = m < 64 ? m : 64;
        for (int k = 0; k < iters; ++k) {
            int s = __shfl(sv, k);
            unsigned u = hb32[(size_t)s * 64 + lane];
            ax += bf_lo(u);
            ay += bf_hi(u);
        }
    }
    const float dn = dinv[node];
    float2 o; o.x = ax * dn; o.y = ay * dn;
    ((float2*)agg)[(size_t)node * 64 + lane] = o;
}

// ---------------- BatchNorm ----------------

__global__ void k_zero_stats(float* __restrict__ stats) {
    int i = threadIdx.x;
    if (i < 256) stats[i] = 0.f;
}

__global__ __launch_bounds__(256) void k_stats(const float* __restrict__ agg,
                                               float* __restrict__ stats) {
    const int c = threadIdx.x & 127;
    const int half = threadIdx.x >> 7;
    float s = 0.f, s2 = 0.f;
    for (int r = blockIdx.x * 2 + half; r < N_NODES; r += gridDim.x * 2) {
        float v = agg[(size_t)r * NHID + c];
        s += v;
        s2 += v * v;
    }
    __shared__ float ls[256], ls2[256];
    ls[threadIdx.x] = s;
    ls2[threadIdx.x] = s2;
    __syncthreads();
    if (half == 0) {
        atomicAdd(&stats[c],       ls[c] + ls[c + 128]);
        atomicAdd(&stats[128 + c], ls2[c] + ls2[c + 128]);
    }
}

__global__ void k_bn_params(const float* __restrict__ stats,
                            const float* __restrict__ gamma,
                            const float* __restrict__ beta,
                            float* __restrict__ ss) {
    int c = threadIdx.x;
    if (c >= NHID) return;
    float mean = stats[c] / (float)N_NODES;
    float var = stats[128 + c] / (float)N_NODES - mean * mean;
    var = fmaxf(var, 0.f);
    float inv = rsqrtf(var + BN_EPS);
    float sc = gamma[c] * inv;
    ss[c] = sc;
    ss[128 + c] = beta[c] - mean * sc;
}

__global__ void k_bn_apply(float* __restrict__ embed,
                           const float* __restrict__ ss) {
    int t = blockIdx.x * blockDim.x + threadIdx.x;
    if (t >= N_NODES * NHID) return;
    int c = t & 127;
    embed[t] = fmaf(embed[t], ss[c], ss[128 + c]);
}

// ---------------- fc head (LDS-staged) ----------------

__global__ __launch_bounds__(256) void k_fc(const float* __restrict__ embed,
                                            const float* __restrict__ fc_w,
                                            const float* __restrict__ fc_b,
                                            float* __restrict__ out) {
    __shared__ float se[32][65];
    __shared__ float sw[8][65];
    __shared__ float sb[8];
    const int tid = threadIdx.x;
    const int row0 = blockIdx.x * 32;
#pragma unroll
    for (int i = 0; i < 2; ++i) {
        int d = tid + i * 256;
        sw[d >> 6][d & 63] = fc_w[d];
    }
    if (tid < 8) sb[tid] = fc_b[tid];
#pragma unroll
    for (int i = 0; i < 8; ++i) {
        int d = tid + i * 256;
        int r = d >> 6, c = d & 63;
        se[r][c] = (row0 + r < N_NODES) ? embed[(size_t)(row0 + r) * NHID + c] : 0.f;
    }
    __syncthreads();
    const int r = tid >> 3, j = tid & 7;
    float s = sb[j];
#pragma unroll
    for (int k = 0; k < NHID / 2; ++k) s = fmaf(se[r][k], sw[j][k], s);
    if (row0 + r < N_NODES) out[(size_t)(row0 + r) * NCLASS + j] = s;
}

// ---------------- launch ----------------

extern "C" void kernel_launch(void* const* d_in, const int* in_sizes, int n_in,
                              void* d_out, int out_size, void* d_ws, size_t ws_size,
                              hipStream_t stream) {
    const float* x     = (const float*)d_in[0];
    const int*   ei    = (const int*)d_in[1];
    const float* W     = (const float*)d_in[2];
    // d_in[3] = b_gc: cancels inside BatchNorm, unused.
    const float* gamma = (const float*)d_in[4];
    const float* beta  = (const float*)d_in[5];
    const float* fc_w  = (const float*)d_in[6];
    const float* fc_b  = (const float*)d_in[7];

    const int* src = ei;
    const int* dst = ei + N_EDGES;

    float* out   = (float*)d_out;
    float* embed = (float*)d_out + (size_t)N_NODES * NCLASS;  // agg lives here

    // workspace layout (~65 MB)
    char* ws = (char*)d_ws;
    size_t o = 0;
    int2* epair = (int2*)(ws + o);                  o += (size_t)N_EDGES * 8;            // 25.6 MB
    unsigned short* hb = (unsigned short*)(ws + o); o += (size_t)N_NODES * NHID * 2;     // 25.6 MB
    int* esrc   = (int*)(ws + o);                   o += (size_t)N_EDGES * 4;            // 12.8 MB
    int* off    = (int*)(ws + o);                   o += (size_t)(N_NODES + 1) * 4;
    float* dinv = (float*)(ws + o);                 o += (size_t)N_NODES * 4;
    unsigned short* Wt = (unsigned short*)(ws + o); o += (size_t)NFEAT * NHID * 2;
    float* stats = (float*)(ws + o);                o += 256 * 4;
    float* ss    = (float*)(ws + o);                o += 256 * 4;
    int* ghist   = (int*)(ws + o);                  o += NBC * 4;
    int* coff    = (int*)(ws + o);                  o += (NBC + 1) * 4;
    int* ccur    = (int*)(ws + o);                  o += NBC * 4;

    // two-level counting sort -> CSR (off, esrc) + dinv
    k_zero_small<<<(NBC + 255) / 256, 256, 0, stream>>>(ghist, NBC);
    k_chist<<<PART_BLOCKS, 256, 0, stream>>>(dst, ghist);
    k_cscan<<<1, 512, 0, stream>>>(ghist, coff, ccur, off);
    k_part<<<PART_BLOCKS, 256, 0, stream>>>(src, dst, ccur, epair);
    k_fine<<<NBC, 256, 0, stream>>>(epair, coff, off, dinv, esrc);

    // hb = bf16(dinv * (x @ W))
    k_wt<<<(NFEAT * NHID + 255) / 256, 256, 0, stream>>>(W, Wt);
    k_gemm<<<(N_NODES + 63) / 64, 256, 0, stream>>>(x, Wt, dinv, hb);

    // aggregation (no atomics)
    k_agg<<<(N_NODES + 3) / 4, 256, 0, stream>>>(off, esrc, dinv, (const unsigned*)hb, embed);

    // BatchNorm
    k_zero_stats<<<1, 256, 0, stream>>>(stats);
    k_stats<<<1024, 256, 0, stream>>>(embed, stats);
    k_bn_params<<<1, 128, 0, stream>>>(stats, gamma, beta, ss);
    k_bn_apply<<<(N_NODES * NHID + 255) / 256, 256, 0, stream>>>(embed, ss);

    // fc head
    k_fc<<<(N_NODES + 31) / 32, 256, 0, stream>>>(embed, fc_w, fc_b, out);
}

// Round 5
// 331.625 us; speedup vs baseline: 17.9936x; 1.2173x over previous
//
#include <hip/hip_runtime.h>
#include <math.h>

#define N_NODES 100000
#define N_EDGES 3200000
#define NFEAT 128
#define NHID 128
#define NCLASS 8
#define BN_EPS 1e-5f
#define NBC 391            // coarse buckets of 256 nodes
#define PART_BLOCKS 782    // ceil(N_EDGES / 4096)

typedef __attribute__((ext_vector_type(8))) short short8;
typedef __attribute__((ext_vector_type(4))) float f32x4;

__device__ __forceinline__ short f2bf(float f) {
    unsigned u = __float_as_uint(f);
    u += 0x7fffu + ((u >> 16) & 1u);   // round-to-nearest-even
    return (short)(u >> 16);
}
__device__ __forceinline__ float bf_lo(unsigned u) { return __uint_as_float(u << 16); }
__device__ __forceinline__ float bf_hi(unsigned u) { return __uint_as_float(u & 0xffff0000u); }

// ---------------- two-level counting sort ----------------

__global__ __launch_bounds__(256) void k_chist(const int* __restrict__ dst,
                                               int* __restrict__ ghist) {
    __shared__ int lh[NBC];
    const int tid = threadIdx.x;
    for (int i = tid; i < NBC; i += 256) lh[i] = 0;
    __syncthreads();
    const int4* dst4 = (const int4*)dst;
    const int q0 = blockIdx.x * 1024 + tid;
#pragma unroll
    for (int i = 0; i < 4; ++i) {
        int q = q0 + i * 256;
        if (q < N_EDGES / 4) {
            int4 d = dst4[q];
            atomicAdd(&lh[d.x >> 8], 1);
            atomicAdd(&lh[d.y >> 8], 1);
            atomicAdd(&lh[d.z >> 8], 1);
            atomicAdd(&lh[d.w >> 8], 1);
        }
    }
    __syncthreads();
    for (int i = tid; i < NBC; i += 256) {
        int c = lh[i];
        if (c) atomicAdd(&ghist[i], c);
    }
}

__global__ __launch_bounds__(512) void k_cscan(const int* __restrict__ ghist,
                                               int* __restrict__ coff,
                                               int* __restrict__ ccur,
                                               int* __restrict__ off) {
    __shared__ int tmp[512];
    const int t = threadIdx.x;
    int v = (t < NBC) ? ghist[t] : 0;
    tmp[t] = v;
    __syncthreads();
    for (int d = 1; d < 512; d <<= 1) {
        int u = (t >= d) ? tmp[t - d] : 0;
        __syncthreads();
        tmp[t] += u;
        __syncthreads();
    }
    int excl = tmp[t] - v;
    if (t < NBC) {
        coff[t] = excl;
        ccur[t] = excl;
    }
    if (t == NBC - 1) {
        coff[NBC] = tmp[t];
        off[N_NODES] = tmp[t];
    }
}

// scatter packed (src<<8 | dst&255) into coarse regions
__global__ __launch_bounds__(256) void k_part(const int* __restrict__ src,
                                              const int* __restrict__ dst,
                                              int* __restrict__ ccur,
                                              unsigned* __restrict__ epack) {
    __shared__ int lh[NBC];
    __shared__ int lbase[NBC];
    const int tid = threadIdx.x;
    for (int i = tid; i < NBC; i += 256) lh[i] = 0;
    __syncthreads();
    const int4* src4 = (const int4*)src;
    const int4* dst4 = (const int4*)dst;
    const int q0 = blockIdx.x * 1024 + tid;
    int4 sv[4], dv[4];
    int rk[16];
    bool val[4];
#pragma unroll
    for (int i = 0; i < 4; ++i) {
        int q = q0 + i * 256;
        val[i] = q < N_EDGES / 4;
        if (val[i]) {
            sv[i] = src4[q];
            dv[i] = dst4[q];
            rk[i * 4 + 0] = atomicAdd(&lh[dv[i].x >> 8], 1);
            rk[i * 4 + 1] = atomicAdd(&lh[dv[i].y >> 8], 1);
            rk[i * 4 + 2] = atomicAdd(&lh[dv[i].z >> 8], 1);
            rk[i * 4 + 3] = atomicAdd(&lh[dv[i].w >> 8], 1);
        }
    }
    __syncthreads();
    for (int i = tid; i < NBC; i += 256) {
        int c = lh[i];
        lbase[i] = c ? atomicAdd(&ccur[i], c) : 0;
    }
    __syncthreads();
#pragma unroll
    for (int i = 0; i < 4; ++i) {
        if (val[i]) {
            epack[lbase[dv[i].x >> 8] + rk[i * 4 + 0]] = ((unsigned)sv[i].x << 8) | (unsigned)(dv[i].x & 255);
            epack[lbase[dv[i].y >> 8] + rk[i * 4 + 1]] = ((unsigned)sv[i].y << 8) | (unsigned)(dv[i].y & 255);
            epack[lbase[dv[i].z >> 8] + rk[i * 4 + 2]] = ((unsigned)sv[i].z << 8) | (unsigned)(dv[i].z & 255);
            epack[lbase[dv[i].w >> 8] + rk[i * 4 + 3]] = ((unsigned)sv[i].w << 8) | (unsigned)(dv[i].w & 255);
        }
    }
}

// per-coarse-bucket fine sort: exact CSR off/dinv/esrc
__global__ __launch_bounds__(256) void k_fine(const unsigned* __restrict__ epack,
                                              const int* __restrict__ coff,
                                              int* __restrict__ off,
                                              float* __restrict__ dinv,
                                              int* __restrict__ esrc) {
    __shared__ int lh[256], lcur[256], lsc[256];
    const int tid = threadIdx.x;
    const int b = blockIdx.x;
    const int node0 = b << 8;
    const int span = min(256, N_NODES - node0);
    lh[tid] = 0;
    __syncthreads();
    const int lo = coff[b], hiEnd = coff[b + 1];
    for (int i = lo + tid; i < hiEnd; i += 256)
        atomicAdd(&lh[epack[i] & 255u], 1);
    __syncthreads();
    int v = lh[tid];
    lsc[tid] = v;
    __syncthreads();
    for (int d = 1; d < 256; d <<= 1) {
        int u = (tid >= d) ? lsc[tid - d] : 0;
        __syncthreads();
        lsc[tid] += u;
        __syncthreads();
    }
    int excl = lsc[tid] - v;
    lcur[tid] = excl;
    if (tid < span) {
        off[node0 + tid] = lo + excl;
        dinv[node0 + tid] = rsqrtf((float)(v + 1));
    }
    __syncthreads();
    for (int i = lo + tid; i < hiEnd; i += 256) {
        unsigned p = epack[i];
        int pos = atomicAdd(&lcur[p & 255u], 1);
        esrc[lo + pos] = (int)(p >> 8);
    }
}

// ---------------- W transpose+convert ----------------

__global__ void k_wt(const float* __restrict__ W, unsigned short* __restrict__ Wt) {
    int idx = blockIdx.x * blockDim.x + threadIdx.x;
    if (idx >= NFEAT * NHID) return;
    int k = idx >> 7, n = idx & 127;
    Wt[n * NFEAT + k] = (unsigned short)f2bf(W[idx]);
}

// ---------------- MFMA GEMM: hb[r] = bf16(dinv[r] * (x @ W)[r]) ----------------

#define WSTRIDE 136
__global__ __launch_bounds__(256) void k_gemm(const float* __restrict__ x,
                                              const unsigned short* __restrict__ Wt,
                                              const float* __restrict__ dinv,
                                              unsigned short* __restrict__ hb) {
    __shared__ short wlds[NHID * WSTRIDE];
    const int tid = threadIdx.x;

    const unsigned* Wt32 = (const unsigned*)Wt;
    unsigned* wl32 = (unsigned*)wlds;
#pragma unroll
    for (int i = 0; i < 32; ++i) {
        int d = tid + i * 256;
        int n = d >> 6, kp = d & 63;
        wl32[n * (WSTRIDE / 2) + kp] = Wt32[d];
    }
    __syncthreads();

    const int wid = tid >> 6, lane = tid & 63;
    const int qw = lane >> 4, lr = lane & 15;
    const int arow = blockIdx.x * 64 + wid * 16 + lr;
    const bool avalid = arow < N_NODES;

    short8 a[4];
#pragma unroll
    for (int ks = 0; ks < 4; ++ks) {
        if (avalid) {
            const float* p = x + (size_t)arow * NFEAT + ks * 32 + qw * 8;
            float4 v0 = *(const float4*)p;
            float4 v1 = *(const float4*)(p + 4);
            short8 t;
            t[0] = f2bf(v0.x); t[1] = f2bf(v0.y); t[2] = f2bf(v0.z); t[3] = f2bf(v0.w);
            t[4] = f2bf(v1.x); t[5] = f2bf(v1.y); t[6] = f2bf(v1.z); t[7] = f2bf(v1.w);
            a[ks] = t;
        } else {
            short8 t;
#pragma unroll
            for (int j = 0; j < 8; ++j) t[j] = 0;
            a[ks] = t;
        }
    }

    f32x4 acc[8];
#pragma unroll
    for (int nt = 0; nt < 8; ++nt) acc[nt] = (f32x4){0.f, 0.f, 0.f, 0.f};

#pragma unroll
    for (int nt = 0; nt < 8; ++nt) {
#pragma unroll
        for (int ks = 0; ks < 4; ++ks) {
            short8 bfr = *(const short8*)&wlds[(nt * 16 + lr) * WSTRIDE + ks * 32 + qw * 8];
            acc[nt] = __builtin_amdgcn_mfma_f32_16x16x32_bf16(a[ks], bfr, acc[nt], 0, 0, 0);
        }
    }

    const int rbase = blockIdx.x * 64 + wid * 16 + qw * 4;
    float dv[4];
#pragma unroll
    for (int j = 0; j < 4; ++j) dv[j] = (rbase + j < N_NODES) ? dinv[rbase + j] : 0.f;
#pragma unroll
    for (int j = 0; j < 4; ++j) {
        int r = rbase + j;
        if (r >= N_NODES) continue;
#pragma unroll
        for (int nt = 0; nt < 8; ++nt)
            hb[(size_t)r * NHID + nt * 16 + lr] = (unsigned short)f2bf(dv[j] * acc[nt][j]);
    }
}

// ---------------- aggregation: 2 edges in flight per wave ----------------
// half-wave (32 lanes x uint2) per edge; zero-row at hb[N_NODES] for tails.

__global__ __launch_bounds__(256) void k_agg(const int* __restrict__ off,
                                             const int* __restrict__ esrc,
                                             const float* __restrict__ dinv,
                                             const uint2* __restrict__ hbq,
                                             float4* __restrict__ agg4) {
    const int node = (blockIdx.x << 2) | (threadIdx.x >> 6);
    const int lane = threadIdx.x & 63;
    const int hl = lane >> 5;   // half-wave 0/1
    const int cl = lane & 31;   // uint2 col within row
    if (node >= N_NODES) return;

    const float dn = dinv[node];
    const int self = hl ? N_NODES : node;   // half 1 reads the zero row
    uint2 u0 = hbq[(size_t)self * 32 + cl];
    float ax = bf_lo(u0.x), ay = bf_hi(u0.x), az = bf_lo(u0.y), aw = bf_hi(u0.y);

    const int begin = off[node], end = off[node + 1];
    for (int base = begin; base < end; base += 64) {
        int pairs = end - base;
        if (pairs > 64) pairs = 64;
        int sv = (lane < pairs) ? esrc[base + lane] : N_NODES;
        const int kmax = (pairs + 1) >> 1;
        for (int k = 0; k < kmax; ++k) {
            int s = __shfl(sv, 2 * k + hl);          // edge 2k (half0) / 2k+1 (half1)
            uint2 u = hbq[(size_t)s * 32 + cl];
            ax += bf_lo(u.x); ay += bf_hi(u.x);
            az += bf_lo(u.y); aw += bf_hi(u.y);
        }
    }
    ax += __shfl_xor(ax, 32);
    ay += __shfl_xor(ay, 32);
    az += __shfl_xor(az, 32);
    aw += __shfl_xor(aw, 32);
    if (hl == 0) {
        float4 o;
        o.x = ax * dn; o.y = ay * dn; o.z = az * dn; o.w = aw * dn;
        agg4[(size_t)node * 32 + cl] = o;
    }
}

// ---------------- BatchNorm stats (float4) ----------------

__global__ __launch_bounds__(256) void k_stats(const float* __restrict__ agg,
                                               float* __restrict__ stats) {
    const int cb = threadIdx.x & 31;   // float4 col
    const int rg = threadIdx.x >> 5;   // 0..7
    const float4* a4 = (const float4*)agg;
    float4 s = {0.f, 0.f, 0.f, 0.f}, s2 = {0.f, 0.f, 0.f, 0.f};
    for (int r = blockIdx.x * 8 + rg; r < N_NODES; r += gridDim.x * 8) {
        float4 v = a4[(size_t)r * 32 + cb];
        s.x += v.x; s.y += v.y; s.z += v.z; s.w += v.w;
        s2.x += v.x * v.x; s2.y += v.y * v.y; s2.z += v.z * v.z; s2.w += v.w * v.w;
    }
    __shared__ float4 ls[256], ls2[256];
    ls[threadIdx.x] = s;
    ls2[threadIdx.x] = s2;
    __syncthreads();
    if (rg == 0) {
        float4 ts = ls[cb], t2 = ls2[cb];
#pragma unroll
        for (int g = 1; g < 8; ++g) {
            float4 v = ls[g * 32 + cb], w = ls2[g * 32 + cb];
            ts.x += v.x; ts.y += v.y; ts.z += v.z; ts.w += v.w;
            t2.x += w.x; t2.y += w.y; t2.z += w.z; t2.w += w.w;
        }
        atomicAdd(&stats[cb * 4 + 0], ts.x);
        atomicAdd(&stats[cb * 4 + 1], ts.y);
        atomicAdd(&stats[cb * 4 + 2], ts.z);
        atomicAdd(&stats[cb * 4 + 3], ts.w);
        atomicAdd(&stats[128 + cb * 4 + 0], t2.x);
        atomicAdd(&stats[128 + cb * 4 + 1], t2.y);
        atomicAdd(&stats[128 + cb * 4 + 2], t2.z);
        atomicAdd(&stats[128 + cb * 4 + 3], t2.w);
    }
}

__global__ void k_bn_params(const float* __restrict__ stats,
                            const float* __restrict__ gamma,
                            const float* __restrict__ beta,
                            float* __restrict__ ss) {
    int c = threadIdx.x;
    if (c >= NHID) return;
    float mean = stats[c] / (float)N_NODES;
    float var = stats[128 + c] / (float)N_NODES - mean * mean;
    var = fmaxf(var, 0.f);
    float inv = rsqrtf(var + BN_EPS);
    float sc = gamma[c] * inv;
    ss[c] = sc;
    ss[128 + c] = beta[c] - mean * sc;
}

// ---------------- fused BN-apply + fc head ----------------
// block = 64 rows; in-place BN on embed, fc from LDS-staged first half.

__global__ __launch_bounds__(256) void k_bnfc(float* __restrict__ embed,
                                              const float* __restrict__ ss,
                                              const float* __restrict__ fc_w,
                                              const float* __restrict__ fc_b,
                                              float* __restrict__ out) {
    __shared__ float se[64][68];
    __shared__ float sw[8][68];
    __shared__ float sb[8];
    const int tid = threadIdx.x;
    const int row0 = blockIdx.x * 64;
    {
        int d = tid;
        sw[d >> 6][d & 63] = fc_w[d];
        d = tid + 256;
        sw[d >> 6][d & 63] = fc_w[d];
        if (tid < 8) sb[tid] = fc_b[tid];
    }
    float4* ef4 = (float4*)embed;
    const float4* ssc4 = (const float4*)ss;
    const float4* ssh4 = (const float4*)(ss + 128);
#pragma unroll
    for (int i = 0; i < 8; ++i) {
        int d = tid + i * 256;     // 0..2047
        int r = d >> 5;            // row within block
        int cb = d & 31;           // float4 col
        int gr = row0 + r;
        if (gr < N_NODES) {
            float4 v = ef4[(size_t)gr * 32 + cb];
            float4 sc = ssc4[cb], sh = ssh4[cb];
            v.x = fmaf(v.x, sc.x, sh.x);
            v.y = fmaf(v.y, sc.y, sh.y);
            v.z = fmaf(v.z, sc.z, sh.z);
            v.w = fmaf(v.w, sc.w, sh.w);
            ef4[(size_t)gr * 32 + cb] = v;
            if (cb < 16) {
                se[r][cb * 4 + 0] = v.x; se[r][cb * 4 + 1] = v.y;
                se[r][cb * 4 + 2] = v.z; se[r][cb * 4 + 3] = v.w;
            }
        } else if (cb < 16) {
            se[r][cb * 4 + 0] = 0.f; se[r][cb * 4 + 1] = 0.f;
            se[r][cb * 4 + 2] = 0.f; se[r][cb * 4 + 3] = 0.f;
        }
    }
    __syncthreads();
    const int r = tid >> 2;
    const int j0 = (tid & 3) * 2;
    const int gr = row0 + r;
#pragma unroll
    for (int jj = 0; jj < 2; ++jj) {
        int j = j0 + jj;
        float s = sb[j];
#pragma unroll
        for (int k = 0; k < 64; ++k) s = fmaf(se[r][k], sw[j][k], s);
        if (gr < N_NODES) out[(size_t)gr * NCLASS + j] = s;
    }
}

// ---------------- launch ----------------

extern "C" void kernel_launch(void* const* d_in, const int* in_sizes, int n_in,
                              void* d_out, int out_size, void* d_ws, size_t ws_size,
                              hipStream_t stream) {
    const float* x     = (const float*)d_in[0];
    const int*   ei    = (const int*)d_in[1];
    const float* W     = (const float*)d_in[2];
    // d_in[3] = b_gc: cancels inside BatchNorm, unused.
    const float* gamma = (const float*)d_in[4];
    const float* beta  = (const float*)d_in[5];
    const float* fc_w  = (const float*)d_in[6];
    const float* fc_b  = (const float*)d_in[7];

    const int* src = ei;
    const int* dst = ei + N_EDGES;

    float* out   = (float*)d_out;
    float* embed = (float*)d_out + (size_t)N_NODES * NCLASS;  // agg lives here

    // workspace layout (~52 MB)
    char* ws = (char*)d_ws;
    size_t o = 0;
    unsigned* epack = (unsigned*)(ws + o);          o += (size_t)N_EDGES * 4;               // 12.8 MB
    unsigned short* hb = (unsigned short*)(ws + o); o += (size_t)(N_NODES + 1) * NHID * 2;  // 25.6 MB + zero row
    o = (o + 255) & ~(size_t)255;
    int* esrc   = (int*)(ws + o);                   o += (size_t)N_EDGES * 4;               // 12.8 MB
    int* off    = (int*)(ws + o);                   o += (size_t)(N_NODES + 1) * 4;
    float* dinv = (float*)(ws + o);                 o += (size_t)N_NODES * 4;
    unsigned short* Wt = (unsigned short*)(ws + o); o += (size_t)NFEAT * NHID * 2;
    float* stats = (float*)(ws + o);                o += 256 * 4;
    float* ss    = (float*)(ws + o);                o += 256 * 4;
    int* ghist   = (int*)(ws + o);                  o += NBC * 4;
    int* coff    = (int*)(ws + o);                  o += (NBC + 1) * 4;
    int* ccur    = (int*)(ws + o);                  o += NBC * 4;

    hipMemsetAsync(ghist, 0, NBC * 4, stream);
    hipMemsetAsync(hb + (size_t)N_NODES * NHID, 0, NHID * 2, stream);  // zero row
    hipMemsetAsync(stats, 0, 256 * 4, stream);

    // two-level counting sort -> CSR (off, esrc) + dinv
    k_chist<<<PART_BLOCKS, 256, 0, stream>>>(dst, ghist);
    k_cscan<<<1, 512, 0, stream>>>(ghist, coff, ccur, off);
    k_part<<<PART_BLOCKS, 256, 0, stream>>>(src, dst, ccur, epack);
    k_fine<<<NBC, 256, 0, stream>>>(epack, coff, off, dinv, esrc);

    // hb = bf16(dinv * (x @ W))
    k_wt<<<(NFEAT * NHID + 255) / 256, 256, 0, stream>>>(W, Wt);
    k_gemm<<<(N_NODES + 63) / 64, 256, 0, stream>>>(x, Wt, dinv, hb);

    // aggregation
    k_agg<<<(N_NODES + 3) / 4, 256, 0, stream>>>(off, esrc, dinv, (const uint2*)hb, (float4*)embed);

    // BatchNorm + fc
    k_stats<<<512, 256, 0, stream>>>(embed, stats);
    k_bn_params<<<1, 128, 0, stream>>>(stats, gamma, beta, ss);
    k_bnfc<<<(N_NODES + 63) / 64, 256, 0, stream>>>(embed, ss, fc_w, fc_b, out);
}

// Round 6
// 313.183 us; speedup vs baseline: 19.0531x; 1.0589x over previous
//
#include <hip/hip_runtime.h>
#include <hip/hip_bf16.h>
#include <math.h>

#define N_NODES 100000
#define N_EDGES 3200000
#define NFEAT 128
#define NHID 128
#define NCLASS 8
#define BN_EPS 1e-5f
#define NBC 391            // coarse buckets of 256 nodes
#define PART_BLOCKS 782    // ceil(N_EDGES / 4096)

typedef __attribute__((ext_vector_type(8))) short short8;
typedef __attribute__((ext_vector_type(4))) float f32x4;

__device__ __forceinline__ short f2bf(float f) {
    __hip_bfloat16 b = __float2bfloat16(f);   // RNE; compiler emits v_cvt[_pk]_bf16_f32
    return *reinterpret_cast<short*>(&b);
}
__device__ __forceinline__ float bf_lo(unsigned u) { return __uint_as_float(u << 16); }
__device__ __forceinline__ float bf_hi(unsigned u) { return __uint_as_float(u & 0xffff0000u); }

// ---------------- two-level counting sort ----------------

__global__ __launch_bounds__(256) void k_chist(const int* __restrict__ dst,
                                               int* __restrict__ ghist) {
    __shared__ int lh[NBC];
    const int tid = threadIdx.x;
    for (int i = tid; i < NBC; i += 256) lh[i] = 0;
    __syncthreads();
    const int4* dst4 = (const int4*)dst;
    const int q0 = blockIdx.x * 1024 + tid;
#pragma unroll
    for (int i = 0; i < 4; ++i) {
        int q = q0 + i * 256;
        if (q < N_EDGES / 4) {
            int4 d = dst4[q];
            atomicAdd(&lh[d.x >> 8], 1);
            atomicAdd(&lh[d.y >> 8], 1);
            atomicAdd(&lh[d.z >> 8], 1);
            atomicAdd(&lh[d.w >> 8], 1);
        }
    }
    __syncthreads();
    for (int i = tid; i < NBC; i += 256) {
        int c = lh[i];
        if (c) atomicAdd(&ghist[i], c);
    }
}

// scan coarse hist; also zero the BN stats buffer (runs well before k_stats)
__global__ __launch_bounds__(512) void k_cscan(const int* __restrict__ ghist,
                                               int* __restrict__ coff,
                                               int* __restrict__ ccur,
                                               int* __restrict__ off,
                                               float* __restrict__ stats) {
    __shared__ int tmp[512];
    const int t = threadIdx.x;
    if (t < 256) stats[t] = 0.f;
    int v = (t < NBC) ? ghist[t] : 0;
    tmp[t] = v;
    __syncthreads();
    for (int d = 1; d < 512; d <<= 1) {
        int u = (t >= d) ? tmp[t - d] : 0;
        __syncthreads();
        tmp[t] += u;
        __syncthreads();
    }
    int excl = tmp[t] - v;
    if (t < NBC) {
        coff[t] = excl;
        ccur[t] = excl;
    }
    if (t == NBC - 1) {
        coff[NBC] = tmp[t];
        off[N_NODES] = tmp[t];
    }
}

// scatter packed (src<<8 | dst&255) into coarse regions
__global__ __launch_bounds__(256) void k_part(const int* __restrict__ src,
                                              const int* __restrict__ dst,
                                              int* __restrict__ ccur,
                                              unsigned* __restrict__ epack) {
    __shared__ int lh[NBC];
    __shared__ int lbase[NBC];
    const int tid = threadIdx.x;
    for (int i = tid; i < NBC; i += 256) lh[i] = 0;
    __syncthreads();
    const int4* src4 = (const int4*)src;
    const int4* dst4 = (const int4*)dst;
    const int q0 = blockIdx.x * 1024 + tid;
    int4 sv[4], dv[4];
    int rk[16];
    bool val[4];
#pragma unroll
    for (int i = 0; i < 4; ++i) {
        int q = q0 + i * 256;
        val[i] = q < N_EDGES / 4;
        if (val[i]) {
            sv[i] = src4[q];
            dv[i] = dst4[q];
            rk[i * 4 + 0] = atomicAdd(&lh[dv[i].x >> 8], 1);
            rk[i * 4 + 1] = atomicAdd(&lh[dv[i].y >> 8], 1);
            rk[i * 4 + 2] = atomicAdd(&lh[dv[i].z >> 8], 1);
            rk[i * 4 + 3] = atomicAdd(&lh[dv[i].w >> 8], 1);
        }
    }
    __syncthreads();
    for (int i = tid; i < NBC; i += 256) {
        int c = lh[i];
        lbase[i] = c ? atomicAdd(&ccur[i], c) : 0;
    }
    __syncthreads();
#pragma unroll
    for (int i = 0; i < 4; ++i) {
        if (val[i]) {
            epack[lbase[dv[i].x >> 8] + rk[i * 4 + 0]] = ((unsigned)sv[i].x << 8) | (unsigned)(dv[i].x & 255);
            epack[lbase[dv[i].y >> 8] + rk[i * 4 + 1]] = ((unsigned)sv[i].y << 8) | (unsigned)(dv[i].y & 255);
            epack[lbase[dv[i].z >> 8] + rk[i * 4 + 2]] = ((unsigned)sv[i].z << 8) | (unsigned)(dv[i].z & 255);
            epack[lbase[dv[i].w >> 8] + rk[i * 4 + 3]] = ((unsigned)sv[i].w << 8) | (unsigned)(dv[i].w & 255);
        }
    }
}

// per-coarse-bucket fine sort: exact CSR off/dinv/esrc
__global__ __launch_bounds__(256) void k_fine(const unsigned* __restrict__ epack,
                                              const int* __restrict__ coff,
                                              int* __restrict__ off,
                                              float* __restrict__ dinv,
                                              int* __restrict__ esrc) {
    __shared__ int lh[256], lcur[256], lsc[256];
    const int tid = threadIdx.x;
    const int b = blockIdx.x;
    const int node0 = b << 8;
    const int span = min(256, N_NODES - node0);
    lh[tid] = 0;
    __syncthreads();
    const int lo = coff[b], hiEnd = coff[b + 1];
    for (int i = lo + tid; i < hiEnd; i += 256)
        atomicAdd(&lh[epack[i] & 255u], 1);
    __syncthreads();
    int v = lh[tid];
    lsc[tid] = v;
    __syncthreads();
    for (int d = 1; d < 256; d <<= 1) {
        int u = (tid >= d) ? lsc[tid - d] : 0;
        __syncthreads();
        lsc[tid] += u;
        __syncthreads();
    }
    int excl = lsc[tid] - v;
    lcur[tid] = excl;
    if (tid < span) {
        off[node0 + tid] = lo + excl;
        dinv[node0 + tid] = rsqrtf((float)(v + 1));
    }
    __syncthreads();
    for (int i = lo + tid; i < hiEnd; i += 256) {
        unsigned p = epack[i];
        int pos = atomicAdd(&lcur[p & 255u], 1);
        esrc[lo + pos] = (int)(p >> 8);
    }
}

// ---------------- W transpose+convert; also zeroes hb's zero-row ----------------

__global__ void k_wt(const float* __restrict__ W, unsigned short* __restrict__ Wt,
                     uint4* __restrict__ hbz) {
    int idx = blockIdx.x * blockDim.x + threadIdx.x;
    if (idx >= NFEAT * NHID) return;
    if (idx < 16) hbz[idx] = (uint4){0u, 0u, 0u, 0u};   // 256 B zero row
    int k = idx >> 7, n = idx & 127;
    Wt[n * NFEAT + k] = (unsigned short)f2bf(W[idx]);
}

// ---------------- MFMA GEMM: hb[r] = bf16(dinv[r] * (x @ W)[r]) ----------------

#define WSTRIDE 136
__global__ __launch_bounds__(256) void k_gemm(const float* __restrict__ x,
                                              const unsigned short* __restrict__ Wt,
                                              const float* __restrict__ dinv,
                                              unsigned short* __restrict__ hb) {
    __shared__ short wlds[NHID * WSTRIDE];
    const int tid = threadIdx.x;

    const unsigned* Wt32 = (const unsigned*)Wt;
    unsigned* wl32 = (unsigned*)wlds;
#pragma unroll
    for (int i = 0; i < 32; ++i) {
        int d = tid + i * 256;
        int n = d >> 6, kp = d & 63;
        wl32[n * (WSTRIDE / 2) + kp] = Wt32[d];
    }
    __syncthreads();

    const int wid = tid >> 6, lane = tid & 63;
    const int qw = lane >> 4, lr = lane & 15;
    const int arow = blockIdx.x * 64 + wid * 16 + lr;
    const bool avalid = arow < N_NODES;

    short8 a[4];
#pragma unroll
    for (int ks = 0; ks < 4; ++ks) {
        if (avalid) {
            const float* p = x + (size_t)arow * NFEAT + ks * 32 + qw * 8;
            float4 v0 = *(const float4*)p;
            float4 v1 = *(const float4*)(p + 4);
            short8 t;
            t[0] = f2bf(v0.x); t[1] = f2bf(v0.y); t[2] = f2bf(v0.z); t[3] = f2bf(v0.w);
            t[4] = f2bf(v1.x); t[5] = f2bf(v1.y); t[6] = f2bf(v1.z); t[7] = f2bf(v1.w);
            a[ks] = t;
        } else {
            short8 t;
#pragma unroll
            for (int j = 0; j < 8; ++j) t[j] = 0;
            a[ks] = t;
        }
    }

    f32x4 acc[8];
#pragma unroll
    for (int nt = 0; nt < 8; ++nt) acc[nt] = (f32x4){0.f, 0.f, 0.f, 0.f};

#pragma unroll
    for (int nt = 0; nt < 8; ++nt) {
#pragma unroll
        for (int ks = 0; ks < 4; ++ks) {
            short8 bfr = *(const short8*)&wlds[(nt * 16 + lr) * WSTRIDE + ks * 32 + qw * 8];
            acc[nt] = __builtin_amdgcn_mfma_f32_16x16x32_bf16(a[ks], bfr, acc[nt], 0, 0, 0);
        }
    }

    const int rbase = blockIdx.x * 64 + wid * 16 + qw * 4;
    float dv[4];
#pragma unroll
    for (int j = 0; j < 4; ++j) dv[j] = (rbase + j < N_NODES) ? dinv[rbase + j] : 0.f;
#pragma unroll
    for (int j = 0; j < 4; ++j) {
        int r = rbase + j;
        if (r >= N_NODES) continue;
#pragma unroll
        for (int nt = 0; nt < 8; ++nt)
            hb[(size_t)r * NHID + nt * 16 + lr] = (unsigned short)f2bf(dv[j] * acc[nt][j]);
    }
}

// ---------------- aggregation: 4 edges in flight per wave ----------------
// half-wave (32 lanes x uint2) per edge, 2 edges per half-wave per iter,
// 8 independent accumulator chains; zero-row at hb[N_NODES] pads tails.

__global__ __launch_bounds__(256) void k_agg(const int* __restrict__ off,
                                             const int* __restrict__ esrc,
                                             const float* __restrict__ dinv,
                                             const uint2* __restrict__ hbq,
                                             float4* __restrict__ agg4) {
    const int node = (blockIdx.x << 2) | (threadIdx.x >> 6);
    const int lane = threadIdx.x & 63;
    const int hl = lane >> 5;   // half-wave 0/1
    const int cl = lane & 31;   // uint2 col within row
    if (node >= N_NODES) return;

    const float dn = dinv[node];
    const int self = hl ? N_NODES : node;   // half 1 reads the zero row
    uint2 u0 = hbq[(size_t)self * 32 + cl];
    float axA = bf_lo(u0.x), ayA = bf_hi(u0.x), azA = bf_lo(u0.y), awA = bf_hi(u0.y);
    float axB = 0.f, ayB = 0.f, azB = 0.f, awB = 0.f;

    const int begin = off[node], end = off[node + 1];
    for (int base = begin; base < end; base += 64) {
        int m = end - base;
        if (m > 64) m = 64;
        int sv = (lane < m) ? esrc[base + lane] : N_NODES;
        const int kmax = (m + 3) >> 2;
        for (int k = 0; k < kmax; ++k) {
            int sA = __shfl(sv, 4 * k + hl);        // edges 4k, 4k+1
            int sB = __shfl(sv, 4 * k + 2 + hl);    // edges 4k+2, 4k+3
            uint2 uA = hbq[(size_t)sA * 32 + cl];
            uint2 uB = hbq[(size_t)sB * 32 + cl];
            axA += bf_lo(uA.x); ayA += bf_hi(uA.x);
            azA += bf_lo(uA.y); awA += bf_hi(uA.y);
            axB += bf_lo(uB.x); ayB += bf_hi(uB.x);
            azB += bf_lo(uB.y); awB += bf_hi(uB.y);
        }
    }
    float ax = axA + axB, ay = ayA + ayB, az = azA + azB, aw = awA + awB;
    ax += __shfl_xor(ax, 32);
    ay += __shfl_xor(ay, 32);
    az += __shfl_xor(az, 32);
    aw += __shfl_xor(aw, 32);
    if (hl == 0) {
        float4 o;
        o.x = ax * dn; o.y = ay * dn; o.z = az * dn; o.w = aw * dn;
        agg4[(size_t)node * 32 + cl] = o;
    }
}

// ---------------- BatchNorm stats (float4) ----------------

__global__ __launch_bounds__(256) void k_stats(const float* __restrict__ agg,
                                               float* __restrict__ stats) {
    const int cb = threadIdx.x & 31;   // float4 col
    const int rg = threadIdx.x >> 5;   // 0..7
    const float4* a4 = (const float4*)agg;
    float4 s = {0.f, 0.f, 0.f, 0.f}, s2 = {0.f, 0.f, 0.f, 0.f};
    for (int r = blockIdx.x * 8 + rg; r < N_NODES; r += gridDim.x * 8) {
        float4 v = a4[(size_t)r * 32 + cb];
        s.x += v.x; s.y += v.y; s.z += v.z; s.w += v.w;
        s2.x += v.x * v.x; s2.y += v.y * v.y; s2.z += v.z * v.z; s2.w += v.w * v.w;
    }
    __shared__ float4 ls[256], ls2[256];
    ls[threadIdx.x] = s;
    ls2[threadIdx.x] = s2;
    __syncthreads();
    if (rg == 0) {
        float4 ts = ls[cb], t2 = ls2[cb];
#pragma unroll
        for (int g = 1; g < 8; ++g) {
            float4 v = ls[g * 32 + cb], w = ls2[g * 32 + cb];
            ts.x += v.x; ts.y += v.y; ts.z += v.z; ts.w += v.w;
            t2.x += w.x; t2.y += w.y; t2.z += w.z; t2.w += w.w;
        }
        atomicAdd(&stats[cb * 4 + 0], ts.x);
        atomicAdd(&stats[cb * 4 + 1], ts.y);
        atomicAdd(&stats[cb * 4 + 2], ts.z);
        atomicAdd(&stats[cb * 4 + 3], ts.w);
        atomicAdd(&stats[128 + cb * 4 + 0], t2.x);
        atomicAdd(&stats[128 + cb * 4 + 1], t2.y);
        atomicAdd(&stats[128 + cb * 4 + 2], t2.z);
        atomicAdd(&stats[128 + cb * 4 + 3], t2.w);
    }
}

__global__ void k_bn_params(const float* __restrict__ stats,
                            const float* __restrict__ gamma,
                            const float* __restrict__ beta,
                            float* __restrict__ ss) {
    int c = threadIdx.x;
    if (c >= NHID) return;
    float mean = stats[c] / (float)N_NODES;
    float var = stats[128 + c] / (float)N_NODES - mean * mean;
    var = fmaxf(var, 0.f);
    float inv = rsqrtf(var + BN_EPS);
    float sc = gamma[c] * inv;
    ss[c] = sc;
    ss[128 + c] = beta[c] - mean * sc;
}

// ---------------- fused BN-apply + fc head ----------------

__global__ __launch_bounds__(256) void k_bnfc(float* __restrict__ embed,
                                              const float* __restrict__ ss,
                                              const float* __restrict__ fc_w,
                                              const float* __restrict__ fc_b,
                                              float* __restrict__ out) {
    __shared__ float se[64][68];
    __shared__ float sw[8][68];
    __shared__ float sb[8];
    const int tid = threadIdx.x;
    const int row0 = blockIdx.x * 64;
    {
        int d = tid;
        sw[d >> 6][d & 63] = fc_w[d];
        d = tid + 256;
        sw[d >> 6][d & 63] = fc_w[d];
        if (tid < 8) sb[tid] = fc_b[tid];
    }
    float4* ef4 = (float4*)embed;
    const float4* ssc4 = (const float4*)ss;
    const float4* ssh4 = (const float4*)(ss + 128);
#pragma unroll
    for (int i = 0; i < 8; ++i) {
        int d = tid + i * 256;     // 0..2047
        int r = d >> 5;            // row within block
        int cb = d & 31;           // float4 col
        int gr = row0 + r;
        if (gr < N_NODES) {
            float4 v = ef4[(size_t)gr * 32 + cb];
            float4 sc = ssc4[cb], sh = ssh4[cb];
            v.x = fmaf(v.x, sc.x, sh.x);
            v.y = fmaf(v.y, sc.y, sh.y);
            v.z = fmaf(v.z, sc.z, sh.z);
            v.w = fmaf(v.w, sc.w, sh.w);
            ef4[(size_t)gr * 32 + cb] = v;
            if (cb < 16) {
                se[r][cb * 4 + 0] = v.x; se[r][cb * 4 + 1] = v.y;
                se[r][cb * 4 + 2] = v.z; se[r][cb * 4 + 3] = v.w;
            }
        } else if (cb < 16) {
            se[r][cb * 4 + 0] = 0.f; se[r][cb * 4 + 1] = 0.f;
            se[r][cb * 4 + 2] = 0.f; se[r][cb * 4 + 3] = 0.f;
        }
    }
    __syncthreads();
    const int r = tid >> 2;
    const int j0 = (tid & 3) * 2;
    const int gr = row0 + r;
#pragma unroll
    for (int jj = 0; jj < 2; ++jj) {
        int j = j0 + jj;
        float s = sb[j];
#pragma unroll
        for (int k = 0; k < 64; ++k) s = fmaf(se[r][k], sw[j][k], s);
        if (gr < N_NODES) out[(size_t)gr * NCLASS + j] = s;
    }
}

// ---------------- launch ----------------

extern "C" void kernel_launch(void* const* d_in, const int* in_sizes, int n_in,
                              void* d_out, int out_size, void* d_ws, size_t ws_size,
                              hipStream_t stream) {
    const float* x     = (const float*)d_in[0];
    const int*   ei    = (const int*)d_in[1];
    const float* W     = (const float*)d_in[2];
    // d_in[3] = b_gc: cancels inside BatchNorm, unused.
    const float* gamma = (const float*)d_in[4];
    const float* beta  = (const float*)d_in[5];
    const float* fc_w  = (const float*)d_in[6];
    const float* fc_b  = (const float*)d_in[7];

    const int* src = ei;
    const int* dst = ei + N_EDGES;

    float* out   = (float*)d_out;
    float* embed = (float*)d_out + (size_t)N_NODES * NCLASS;  // agg lives here

    // workspace layout (~52 MB)
    char* ws = (char*)d_ws;
    size_t o = 0;
    unsigned* epack = (unsigned*)(ws + o);          o += (size_t)N_EDGES * 4;               // 12.8 MB
    unsigned short* hb = (unsigned short*)(ws + o); o += (size_t)(N_NODES + 1) * NHID * 2;  // 25.6 MB + zero row
    o = (o + 255) & ~(size_t)255;
    int* esrc   = (int*)(ws + o);                   o += (size_t)N_EDGES * 4;               // 12.8 MB
    int* off    = (int*)(ws + o);                   o += (size_t)(N_NODES + 1) * 4;
    float* dinv = (float*)(ws + o);                 o += (size_t)N_NODES * 4;
    unsigned short* Wt = (unsigned short*)(ws + o); o += (size_t)NFEAT * NHID * 2;
    float* stats = (float*)(ws + o);                o += 256 * 4;
    float* ss    = (float*)(ws + o);                o += 256 * 4;
    int* ghist   = (int*)(ws + o);                  o += NBC * 4;
    int* coff    = (int*)(ws + o);                  o += (NBC + 1) * 4;
    int* ccur    = (int*)(ws + o);                  o += NBC * 4;

    hipMemsetAsync(ghist, 0, NBC * 4, stream);

    // two-level counting sort -> CSR (off, esrc) + dinv
    k_chist<<<PART_BLOCKS, 256, 0, stream>>>(dst, ghist);
    k_cscan<<<1, 512, 0, stream>>>(ghist, coff, ccur, off, stats);
    k_part<<<PART_BLOCKS, 256, 0, stream>>>(src, dst, ccur, epack);
    k_fine<<<NBC, 256, 0, stream>>>(epack, coff, off, dinv, esrc);

    // hb = bf16(dinv * (x @ W))
    k_wt<<<(NFEAT * NHID + 255) / 256, 256, 0, stream>>>(W, Wt, (uint4*)(hb + (size_t)N_NODES * NHID));
    k_gemm<<<(N_NODES + 63) / 64, 256, 0, stream>>>(x, Wt, dinv, hb);

    // aggregation
    k_agg<<<(N_NODES + 3) / 4, 256, 0, stream>>>(off, esrc, dinv, (const uint2*)hb, (float4*)embed);

    // BatchNorm + fc
    k_stats<<<512, 256, 0, stream>>>(embed, stats);
    k_bn_params<<<1, 128, 0, stream>>>(stats, gamma, beta, ss);
    k_bnfc<<<(N_NODES + 63) / 64, 256, 0, stream>>>(embed, ss, fc_w, fc_b, out);
}